// Round 6
// baseline (221.031 us; speedup 1.0000x reference)
//
#include <hip/hip_runtime.h>

#define LOG2E 1.4426950408889634f

// ---------- bf16 helpers (raw ushort representation) ----------
__device__ __forceinline__ float b2f(unsigned short u) {
    unsigned int v = ((unsigned int)u) << 16;
    return __builtin_bit_cast(float, v);
}
__device__ __forceinline__ unsigned short f2b(float f) {
    unsigned int u = __builtin_bit_cast(unsigned int, f);
    u += 0x7fffu + ((u >> 16) & 1u);   // round-to-nearest-even
    return (unsigned short)(u >> 16);
}
__device__ __forceinline__ float fexp(float x) {           // e^x
    return __builtin_amdgcn_exp2f(x * LOG2E);
}
__device__ __forceinline__ float silu_f(float x) {
    return x * __builtin_amdgcn_rcpf(1.0f + fexp(-x));
}

// async global->LDS 16B per lane; lptr must be wave-uniform (dest = base + lane*16)
typedef const __attribute__((address_space(1))) unsigned int* gas_t;
typedef __attribute__((address_space(3))) unsigned int* las_t;
__device__ __forceinline__ void gl2lds16(const unsigned short* g, unsigned short* l) {
    __builtin_amdgcn_global_load_lds((gas_t)(const void*)g, (las_t)(void*)l, 16, 0, 0);
}

// ---------- fused fp32 -> bf16 cast for all 4 arrays, one launch ----------
__global__ __launch_bounds__(256) void cvt_all_k(const float* __restrict__ x,
                                                 const float* __restrict__ W_in,
                                                 const float* __restrict__ W_out,
                                                 const float* __restrict__ W_x,
                                                 unsigned short* __restrict__ xb,
                                                 unsigned short* __restrict__ wib,
                                                 unsigned short* __restrict__ wob,
                                                 unsigned short* __restrict__ wxb) {
    int b = blockIdx.x;
    const float* src;
    unsigned short* dst;
    if (b < 4096)       { src = x;     dst = xb;  }
    else if (b < 8192)  { src = W_in;  dst = wib; b -= 4096; }
    else if (b < 10240) { src = W_out; dst = wob; b -= 8192; }
    else                { src = W_x;   dst = wxb; b -= 10240; }
    int i = b * 256 + threadIdx.x;
    float4 v = ((const float4*)src)[i];
    *(ushort4*)(dst + (size_t)i * 4) = make_ushort4(f2b(v.x), f2b(v.y), f2b(v.z), f2b(v.w));
}

// ---------- bf16 MFMA GEMM: C[M,N] = A[M,K] * B[N,K]^T ----------
// 128x128 tile, BK=64, global_load_lds w=16, XOR-swizzled (conflicts=0, verified R3).
typedef __bf16 bf16x8 __attribute__((ext_vector_type(8)));
typedef float  fx4    __attribute__((ext_vector_type(4)));
typedef int    ix4    __attribute__((ext_vector_type(4)));
union FragU { ix4 i; bf16x8 b; };

template <bool OUT_BF16>
__global__ __launch_bounds__(256) void gemm_bt(const unsigned short* __restrict__ A,
                                               const unsigned short* __restrict__ B,
                                               void* __restrict__ C, int N, int K) {
    __shared__ __align__(16) unsigned short sA[128 * 64];
    __shared__ __align__(16) unsigned short sB[128 * 64];
    const int tid  = threadIdx.x;
    const int lane = tid & 63, wave = tid >> 6;
    const int bm = blockIdx.y * 128, bn = blockIdx.x * 128;
    const int wm = (wave >> 1) * 64, wn = (wave & 1) * 64;
    const int row16 = lane & 15, quad = lane >> 4;
    const int srow = lane >> 3;
    const int sc16 = (lane & 7) ^ srow;
    const unsigned short* gA = A + (size_t)(bm + wave * 32 + srow) * K + sc16 * 8;
    const unsigned short* gB = B + (size_t)(bn + wave * 32 + srow) * K + sc16 * 8;
    unsigned short* lA = sA + (wave * 4) * 512;   // wave-uniform
    unsigned short* lB = sB + (wave * 4) * 512;
    fx4 acc[4][4] = {};

    for (int kt = 0; kt < K; kt += 64) {
#pragma unroll
        for (int it = 0; it < 4; ++it) {
            gl2lds16(gA + (size_t)it * 8 * K + kt, lA + it * 512);
            gl2lds16(gB + (size_t)it * 8 * K + kt, lB + it * 512);
        }
        __syncthreads();
#pragma unroll
        for (int kk = 0; kk < 64; kk += 32) {
            FragU af[4], bf[4];
#pragma unroll
            for (int t = 0; t < 4; ++t) {
                int ra = wm + t * 16 + row16;
                af[t].i = *(const ix4*)(sA + ra * 64 + ((quad + (kk >> 3)) ^ (ra & 7)) * 8);
            }
#pragma unroll
            for (int t = 0; t < 4; ++t) {
                int rb = wn + t * 16 + row16;
                bf[t].i = *(const ix4*)(sB + rb * 64 + ((quad + (kk >> 3)) ^ (rb & 7)) * 8);
            }
#pragma unroll
            for (int tm = 0; tm < 4; ++tm)
#pragma unroll
                for (int tn = 0; tn < 4; ++tn)
                    acc[tm][tn] = __builtin_amdgcn_mfma_f32_16x16x32_bf16(
                        af[tm].b, bf[tn].b, acc[tm][tn], 0, 0, 0);
        }
        __syncthreads();
    }
#pragma unroll
    for (int tm = 0; tm < 4; ++tm) {
        int row0 = bm + wm + tm * 16 + quad * 4;
#pragma unroll
        for (int tn = 0; tn < 4; ++tn) {
            int col = bn + wn + tn * 16 + row16;
#pragma unroll
            for (int r = 0; r < 4; ++r) {
                float v = acc[tm][tn][r];
                if (OUT_BF16)
                    ((unsigned short*)C)[(size_t)(row0 + r) * N + col] = f2b(v);
                else
                    ((float*)C)[(size_t)(row0 + r) * N + col] = v;
            }
        }
    }
}

// ---------- narrow GEMM for C[M,1024]: 128x64 tile, 512 blocks = 2/CU ----------
__global__ __launch_bounds__(256) void gemm_bt_n64(const unsigned short* __restrict__ A,
                                                   const unsigned short* __restrict__ B,
                                                   float* __restrict__ C, int N, int K) {
    __shared__ __align__(16) unsigned short sA[128 * 64];
    __shared__ __align__(16) unsigned short sB[64 * 64];
    const int tid  = threadIdx.x;
    const int lane = tid & 63, wave = tid >> 6;
    const int bm = blockIdx.y * 128, bn = blockIdx.x * 64;
    const int wm = wave * 32;
    const int row16 = lane & 15, quad = lane >> 4;
    const int srow = lane >> 3;
    const int sc16 = (lane & 7) ^ srow;
    const unsigned short* gA = A + (size_t)(bm + wave * 32 + srow) * K + sc16 * 8;
    const unsigned short* gB = B + (size_t)(bn + wave * 16 + srow) * K + sc16 * 8;
    unsigned short* lA = sA + (wave * 4) * 512;
    unsigned short* lB = sB + (wave * 2) * 512;
    fx4 acc[2][4] = {};

    for (int kt = 0; kt < K; kt += 64) {
#pragma unroll
        for (int it = 0; it < 4; ++it)
            gl2lds16(gA + (size_t)it * 8 * K + kt, lA + it * 512);
#pragma unroll
        for (int it = 0; it < 2; ++it)
            gl2lds16(gB + (size_t)it * 8 * K + kt, lB + it * 512);
        __syncthreads();
#pragma unroll
        for (int kk = 0; kk < 64; kk += 32) {
            FragU af[2], bf[4];
#pragma unroll
            for (int t = 0; t < 2; ++t) {
                int ra = wm + t * 16 + row16;
                af[t].i = *(const ix4*)(sA + ra * 64 + ((quad + (kk >> 3)) ^ (ra & 7)) * 8);
            }
#pragma unroll
            for (int t = 0; t < 4; ++t) {
                int rb = t * 16 + row16;
                bf[t].i = *(const ix4*)(sB + rb * 64 + ((quad + (kk >> 3)) ^ (rb & 7)) * 8);
            }
#pragma unroll
            for (int tm = 0; tm < 2; ++tm)
#pragma unroll
                for (int tn = 0; tn < 4; ++tn)
                    acc[tm][tn] = __builtin_amdgcn_mfma_f32_16x16x32_bf16(
                        af[tm].b, bf[tn].b, acc[tm][tn], 0, 0, 0);
        }
        __syncthreads();
    }
#pragma unroll
    for (int tm = 0; tm < 2; ++tm) {
        int row0 = bm + wm + tm * 16 + quad * 4;
#pragma unroll
        for (int tn = 0; tn < 4; ++tn) {
            int col = bn + tn * 16 + row16;
#pragma unroll
            for (int r = 0; r < 4; ++r)
                C[(size_t)(row0 + r) * N + col] = acc[tm][tn][r];
        }
    }
}

// ---------- fused middle: conv+silu -> LDS xc -> xproj MFMA -> delta/G -> SSM -> y2 ----------
// grid 512 blocks x 256 thr; block owns 8 rows (R5: 16 rows @ 1 blk/CU was
// latency-bound, Occupancy 9.4%). LDS ~45.9 KB -> 2 blocks/CU, 8 waves/CU.
// LDS xc layout: row-major 8x2048 bf16 with 16B-col XOR swizzle (phys c16 = c16 ^ (j&7)).
__global__ __launch_bounds__(256) void fused_mid_k(const unsigned short* __restrict__ xz,
                                                   const float* __restrict__ cw,
                                                   const unsigned short* __restrict__ wxb,
                                                   const float* __restrict__ Alog,
                                                   const float* __restrict__ Dv,
                                                   unsigned short* __restrict__ y2) {
    __shared__ __align__(16) unsigned short sxc[8 * 2048];    // 32 KB
    __shared__ float sX[4][16][49];                            // 12.5 KB
    __shared__ float sdg[8 * 17];
    const int tid  = threadIdx.x;
    const int lane = tid & 63, wave = tid >> 6;
    const int row16 = lane & 15, quad = lane >> 4;
    const int m0 = blockIdx.x * 8;

    // ---- phase 1: conv(K=4, causal) + silu for 8 rows x 2048 ch ----
    {
        const float4* cw4 = (const float4*)cw;
        float w[8][4];
#pragma unroll
        for (int c = 0; c < 8; ++c) {
            float4 t4 = cw4[tid * 8 + c];
            w[c][0] = t4.x; w[c][1] = t4.y; w[c][2] = t4.z; w[c][3] = t4.w;
        }
#pragma unroll
        for (int j = 0; j < 8; ++j) {
            const int m = m0 + j, s = m & 2047;
            float acc[8] = {0, 0, 0, 0, 0, 0, 0, 0};
#pragma unroll
            for (int k = 0; k < 4; ++k) {
                if (s - 3 + k >= 0) {          // row-uniform branch
                    const unsigned short* p = xz + (size_t)(m - 3 + k) * 4096 + tid * 8;
                    ushort4 a = *(const ushort4*)p;
                    ushort4 b = *(const ushort4*)(p + 4);
                    float v[8] = {b2f(a.x), b2f(a.y), b2f(a.z), b2f(a.w),
                                  b2f(b.x), b2f(b.y), b2f(b.z), b2f(b.w)};
#pragma unroll
                    for (int c = 0; c < 8; ++c) acc[c] += v[c] * w[c][k];
                }
            }
            unsigned short* q = sxc + j * 2048 + ((tid ^ (j & 7)) * 8);
            *(ushort4*)q       = make_ushort4(f2b(silu_f(acc[0])), f2b(silu_f(acc[1])),
                                              f2b(silu_f(acc[2])), f2b(silu_f(acc[3])));
            *(ushort4*)(q + 4) = make_ushort4(f2b(silu_f(acc[4])), f2b(silu_f(acc[5])),
                                              f2b(silu_f(acc[6])), f2b(silu_f(acc[7])));
        }
    }
    __syncthreads();

    // ---- phase 2: xproj = xc @ Wx^T (N=33 pad 48); wave = K-quarter; A from LDS ----
    // A rows 8..15 duplicate rows 0..7 (row16&7); their D rows are discarded —
    // MFMA output rows are independent dot products, so no contamination.
    {
        fx4 acc[3] = {};
        const unsigned short* bp = wxb + (size_t)row16 * 2048 + wave * 512 + quad * 8;
        const int arow = row16 & 7;
        const int cbase = wave * 64 + quad;
#pragma unroll 4
        for (int kk = 0; kk < 512; kk += 32) {
            FragU a, b0, b1, b2;
            int c16 = cbase + (kk >> 3);
            a.i  = *(const ix4*)(sxc + arow * 2048 + ((c16 ^ (arow & 7)) * 8));
            b0.i = *(const ix4*)(bp + kk);
            b1.i = *(const ix4*)(bp + 16 * 2048 + kk);
            b2.i = *(const ix4*)(bp + 32 * 2048 + kk);
            acc[0] = __builtin_amdgcn_mfma_f32_16x16x32_bf16(a.b, b0.b, acc[0], 0, 0, 0);
            acc[1] = __builtin_amdgcn_mfma_f32_16x16x32_bf16(a.b, b1.b, acc[1], 0, 0, 0);
            acc[2] = __builtin_amdgcn_mfma_f32_16x16x32_bf16(a.b, b2.b, acc[2], 0, 0, 0);
        }
#pragma unroll
        for (int t = 0; t < 3; ++t)
#pragma unroll
            for (int r = 0; r < 4; ++r)
                sX[wave][quad * 4 + r][t * 16 + row16] = acc[t][r];
    }
    __syncthreads();
    for (int idx = tid; idx < 136; idx += 256) {
        int rr = idx / 17, q = idx - rr * 17;
        float o;
        if (q == 0) {
            float v = sX[0][rr][0] + sX[1][rr][0] + sX[2][rr][0] + sX[3][rr][0];
            o = (v > 20.f) ? v : log1pf(fexp(v));          // softplus(delta_raw)
        } else {
            float bs = sX[0][rr][q]      + sX[1][rr][q]      + sX[2][rr][q]      + sX[3][rr][q];
            float cs = sX[0][rr][q + 16] + sX[1][rr][q + 16] + sX[2][rr][q + 16] + sX[3][rr][q + 16];
            o = bs * cs;                                   // G[n] = B[n]*C[n]
        }
        sdg[rr * 17 + q] = o;
    }
    __syncthreads();

    // ---- phase 3: SSM pointwise; 2 passes x 4 channels/thread, A_log in regs ----
#pragma unroll 1
    for (int p = 0; p < 2; ++p) {
        const int ch0 = p * 1024 + tid * 4;
        float a2[4][16];
#pragma unroll
        for (int c = 0; c < 4; ++c) {
            const float4* ar = (const float4*)(Alog + (size_t)(ch0 + c) * 16);
#pragma unroll
            for (int n4 = 0; n4 < 4; ++n4) {
                float4 t4 = ar[n4];
                a2[c][n4 * 4 + 0] = -fexp(t4.x) * LOG2E;
                a2[c][n4 * 4 + 1] = -fexp(t4.y) * LOG2E;
                a2[c][n4 * 4 + 2] = -fexp(t4.z) * LOG2E;
                a2[c][n4 * 4 + 3] = -fexp(t4.w) * LOG2E;
            }
        }
        float4 dvv = *(const float4*)(Dv + ch0);
        float dv[4] = {dvv.x, dvv.y, dvv.z, dvv.w};
        const int c16 = ch0 >> 3, sub = ch0 & 7;
#pragma unroll 1
        for (int j = 0; j < 8; ++j) {
            const int m = m0 + j;
            float delta = sdg[j * 17];
            float Gr[16];
#pragma unroll
            for (int n = 0; n < 16; ++n) Gr[n] = sdg[j * 17 + 1 + n];
            ushort4 xu = *(const ushort4*)(sxc + j * 2048 + ((c16 ^ (j & 7)) * 8) + sub);
            ushort4 zu = *(const ushort4*)(xz + (size_t)m * 4096 + 2048 + ch0);
            float xcv[4] = {b2f(xu.x), b2f(xu.y), b2f(xu.z), b2f(xu.w)};
            float zv[4]  = {b2f(zu.x), b2f(zu.y), b2f(zu.z), b2f(zu.w)};
            unsigned short ov[4];
#pragma unroll
            for (int c = 0; c < 4; ++c) {
                float ssum = 0.f;
#pragma unroll
                for (int n = 0; n < 16; ++n)
                    ssum += Gr[n] * __builtin_amdgcn_exp2f(delta * a2[c][n]);
                float y = xcv[c] * (dv[c] + ssum);
                ov[c] = f2b(y * silu_f(zv[c]));
            }
            *(ushort4*)(y2 + (size_t)m * 2048 + ch0) = make_ushort4(ov[0], ov[1], ov[2], ov[3]);
        }
    }
}

// ---------- launch ----------
extern "C" void kernel_launch(void* const* d_in, const int* in_sizes, int n_in,
                              void* d_out, int out_size, void* d_ws, size_t ws_size,
                              hipStream_t stream) {
    const float* x      = (const float*)d_in[0];   // (2,2048,1024)
    const float* W_in   = (const float*)d_in[1];   // (4096,1024)
    const float* conv_w = (const float*)d_in[2];   // (2048,1,4)
    const float* W_x    = (const float*)d_in[3];   // (33,2048)
    const float* A_log  = (const float*)d_in[4];   // (2048,16)
    const float* Dvec   = (const float*)d_in[5];   // (2048,)
    const float* W_out  = (const float*)d_in[6];   // (1024,2048)

    char* ws = (char*)d_ws;
    unsigned short* xb  = (unsigned short*)(ws);              //  8,388,608  x bf16
    unsigned short* wib = (unsigned short*)(ws + 8388608);    //  8,388,608  W_in bf16
    unsigned short* wob = (unsigned short*)(ws + 16777216);   //  4,194,304  W_out bf16
    unsigned short* xz  = (unsigned short*)(ws + 20971520);   // 33,554,432  xz bf16 (4096x4096)
    unsigned short* y2  = (unsigned short*)(ws + 54525952);   // 16,777,216  y2 bf16 (4096x2048)
    unsigned short* wxb = (unsigned short*)(ws + 71303168);   //    196,608  Wx bf16 (48x2048 padded)

    cvt_all_k<<<10306, 256, 0, stream>>>(x, W_in, W_out, W_x, xb, wib, wob, wxb);
    // xz[m,i] = sum_h x[m,h] * W_in[i,h]
    gemm_bt<true><<<dim3(32, 32), 256, 0, stream>>>(xb, wib, xz, 4096, 1024);
    // conv+silu -> xproj -> delta/G -> SSM gate, all in one dispatch
    fused_mid_k<<<512, 256, 0, stream>>>(xz, conv_w, wxb, A_log, Dvec, y2);
    // out[m,h] = sum_i y2[m,i] * W_out[h,i]
    gemm_bt_n64<<<dim3(16, 32), 256, 0, stream>>>(y2, wob, (float*)d_out, 1024, 2048);
}